// Round 5
// baseline (196.571 us; speedup 1.0000x reference)
//
#include <hip/hip_runtime.h>
#include <stdint.h>
#include <math.h>

#define H 8
#define NSEQ 8192
#define D 64
#define SCALE 0.125f
#define EPSF 1.1920928955078125e-07f

typedef short v8s __attribute__((ext_vector_type(8)));
typedef float v4f __attribute__((ext_vector_type(4)));
typedef unsigned short ushort_t;

#define MFMA16(a,b,c) __builtin_amdgcn_mfma_f32_16x16x32_bf16((a),(b),(c),0,0,0)
// swizzled LDS byte address: 128B row stride, XOR bank swizzle (G4)
#define SWZ(row, cb) (((row)*128) + ((cb) ^ ((((row)&7))<<4)))

__device__ __forceinline__ ushort_t f2bf(float f){
  union { float f; unsigned int u; } c; c.f = f;
  unsigned int u = c.u + 0x7FFFu + ((c.u >> 16) & 1u);   // RNE
  return (ushort_t)(u >> 16);
}

// ---------------- 0a. fused prepass+hash for Q,K ----------------
// One 64-row tile per block: coalesced fp32 load -> LDS, bf16 convert+store,
// then 64 threads hash serially (EXACT same fmaf order as the passing kernel).
__global__ __launch_bounds__(256) void prep_hash(
    const float* __restrict__ q, const float* __restrict__ k,
    const float* __restrict__ proj,
    ushort_t* __restrict__ qb, ushort_t* __restrict__ kb,
    int* __restrict__ hq, int* __restrict__ hk)
{
  __shared__ float tile[64][65];
  __shared__ float pj[448];
  const int bid = blockIdx.x;            // 2048 = 2 tensors x 1024 tiles
  const int isk = bid & 1;
  const int tix = bid >> 1;
  const int rowbase = tix << 6;
  const float* src = isk ? k : q;
  ushort_t* dstb = isk ? kb : qb;
  int* dsth = isk ? hk : hq;
  const int t = threadIdx.x;
  for (int i = t; i < 448; i += 256) pj[i] = proj[i];
  {
    const int r = t >> 2, cg = (t & 3) << 4;
    const float* s = src + (size_t)(rowbase + r)*64 + cg;
    float4 f0 = *(const float4*)(s);
    float4 f1 = *(const float4*)(s + 4);
    float4 f2 = *(const float4*)(s + 8);
    float4 f3 = *(const float4*)(s + 12);
    // fp32 -> LDS (scalar stores keep [64][65] pad; 2-way bank at worst)
    tile[r][cg+0]=f0.x;  tile[r][cg+1]=f0.y;  tile[r][cg+2]=f0.z;  tile[r][cg+3]=f0.w;
    tile[r][cg+4]=f1.x;  tile[r][cg+5]=f1.y;  tile[r][cg+6]=f1.z;  tile[r][cg+7]=f1.w;
    tile[r][cg+8]=f2.x;  tile[r][cg+9]=f2.y;  tile[r][cg+10]=f2.z; tile[r][cg+11]=f2.w;
    tile[r][cg+12]=f3.x; tile[r][cg+13]=f3.y; tile[r][cg+14]=f3.z; tile[r][cg+15]=f3.w;
    uint4 o0, o1;
    o0.x = (unsigned int)f2bf(f0.x) | ((unsigned int)f2bf(f0.y) << 16);
    o0.y = (unsigned int)f2bf(f0.z) | ((unsigned int)f2bf(f0.w) << 16);
    o0.z = (unsigned int)f2bf(f1.x) | ((unsigned int)f2bf(f1.y) << 16);
    o0.w = (unsigned int)f2bf(f1.z) | ((unsigned int)f2bf(f1.w) << 16);
    o1.x = (unsigned int)f2bf(f2.x) | ((unsigned int)f2bf(f2.y) << 16);
    o1.y = (unsigned int)f2bf(f2.z) | ((unsigned int)f2bf(f2.w) << 16);
    o1.z = (unsigned int)f2bf(f3.x) | ((unsigned int)f2bf(f3.y) << 16);
    o1.w = (unsigned int)f2bf(f3.z) | ((unsigned int)f2bf(f3.w) << 16);
    *(uint4*)(dstb + (size_t)(rowbase + r)*64 + cg) = o0;
    *(uint4*)(dstb + (size_t)(rowbase + r)*64 + cg + 8) = o1;
  }
  __syncthreads();
  if (t < 64){
    float dot[7] = {0,0,0,0,0,0,0};
    for (int d = 0; d < 64; ++d){
      float x = tile[t][d];
#pragma unroll
      for (int p = 0; p < 7; ++p) dot[p] = fmaf(x, pj[d*7+p], dot[p]);
    }
    int b = 0;
#pragma unroll
    for (int p = 0; p < 7; ++p) if (dot[p] > 0.0f) b |= (1 << p);
    dsth[rowbase + t] = b ^ (b >> 1);          // gray code == _PERM
  }
}

// ---------------- 0b. bf16 prepass for V ----------------
__global__ __launch_bounds__(256) void prep_v(
    const float* __restrict__ v, ushort_t* __restrict__ vb)
{
  int gid = blockIdx.x * 256 + threadIdx.x;     // 2048 blocks x 256 x 8 els
  size_t off = (size_t)gid * 8;
  float4 f0 = *(const float4*)(v + off);
  float4 f1 = *(const float4*)(v + off + 4);
  uint4 o;
  o.x = (unsigned int)f2bf(f0.x) | ((unsigned int)f2bf(f0.y) << 16);
  o.y = (unsigned int)f2bf(f0.z) | ((unsigned int)f2bf(f0.w) << 16);
  o.z = (unsigned int)f2bf(f1.x) | ((unsigned int)f2bf(f1.y) << 16);
  o.w = (unsigned int)f2bf(f1.z) | ((unsigned int)f2bf(f1.w) << 16);
  *(uint4*)(vb + off) = o;
}

// ---------------- 2. Threefry-2x32-20 sampled indices (partitionable PRNG) ----------------
__device__ __forceinline__ void tf2x32(uint32_t k0, uint32_t k1,
                                       uint32_t x0, uint32_t x1,
                                       uint32_t& o0, uint32_t& o1)
{
  uint32_t ks0 = k0, ks1 = k1, ks2 = k0 ^ k1 ^ 0x1BD11BDAu;
  x0 += ks0; x1 += ks1;
#define RND(r) { x0 += x1; x1 = (x1 << (r)) | (x1 >> (32-(r))); x1 ^= x0; }
  RND(13) RND(15) RND(26) RND(6)  x0 += ks1; x1 += ks2 + 1u;
  RND(17) RND(29) RND(16) RND(24) x0 += ks2; x1 += ks0 + 2u;
  RND(13) RND(15) RND(26) RND(6)  x0 += ks0; x1 += ks1 + 3u;
  RND(17) RND(29) RND(16) RND(24) x0 += ks1; x1 += ks2 + 4u;
  RND(13) RND(15) RND(26) RND(6)  x0 += ks2; x1 += ks0 + 5u;
#undef RND
  o0 = x0; o1 = x1;
}

__global__ __launch_bounds__(256) void sample_kernel(int* __restrict__ s100, int* __restrict__ s101)
{
  int j = blockIdx.x * blockDim.x + threadIdx.x;
  int level, span, idx; int* out;
  if (j < 2048)      { level = 100; span = 4096; out = s100; idx = j; }
  else if (j < 6144) { level = 101; span = 2048; out = s101; idx = j - 2048; }
  else return;
  uint32_t r0, r1; tf2x32(0u, 42u, 0u, (uint32_t)level, r0, r1);
  uint32_t k20, k21; tf2x32(r0, r1, 0u, 1u, k20, k21);
  uint32_t o0, o1; tf2x32(k20, k21, 0u, (uint32_t)idx, o0, o1);
  uint32_t bits = o0 ^ o1;
  out[idx] = (int)(bits % (uint32_t)span);
}

// ---------------- 3. stable counting sort (argsort by hash) ----------------
__global__ __launch_bounds__(64) void sort_kernel(
    const int* __restrict__ hq, const int* __restrict__ hk,
    int* __restrict__ q100, int* __restrict__ k100,
    int* __restrict__ q101, int* __restrict__ k101)
{
  __shared__ unsigned short hist[64][128];
  __shared__ unsigned int   off [64][128];
  __shared__ int bstart[128];
  const int bid = blockIdx.x, t = threadIdx.x;
  const int* src; int n, base; int* out;
  if (bid < 8)       { int h = bid;     src = hq + h*NSEQ + 4096;          n = 4096; base = 4096;          out = q100 + h*4096; }
  else if (bid < 16) { int h = bid - 8; src = hk + h*NSEQ;                 n = 4096; base = 0;             out = k100 + h*4096; }
  else if (bid < 32) { int id = bid-16; int h = id>>1, p = id&1;
                       src = hq + h*NSEQ + p*4096 + 2048;                  n = 2048; base = p*4096 + 2048; out = q101 + id*2048; }
  else               { int id = bid-32; int h = id>>1, p = id&1;
                       src = hk + h*NSEQ + p*4096;                         n = 2048; base = p*4096;       out = k101 + id*2048; }
  const int chunk = n >> 6;
  for (int b = 0; b < 128; ++b) hist[t][b] = 0;
  __syncthreads();
  const int* mysrc = src + t * chunk;
  for (int i = 0; i < chunk; ++i) hist[t][mysrc[i]]++;
  __syncthreads();
  for (int bb = t; bb < 128; bb += 64){
    int s = 0;
    for (int tt = 0; tt < 64; ++tt) s += hist[tt][bb];
    bstart[bb] = s;
  }
  __syncthreads();
  if (t == 0){
    int run = 0;
    for (int b = 0; b < 128; ++b){ int c = bstart[b]; bstart[b] = run; run += c; }
  }
  __syncthreads();
  for (int bb = t; bb < 128; bb += 64){
    unsigned int run = bstart[bb];
    for (int tt = 0; tt < 64; ++tt){ off[tt][bb] = run; run += hist[tt][bb]; }
  }
  __syncthreads();
  for (int i = 0; i < chunk; ++i){
    int hsh = mysrc[i];
    unsigned int pos = off[t][hsh]++;
    out[pos] = base + t * chunk + i;
  }
}

// ================= shared MFMA flash helpers =================
// Key axis in P/VT is PERMUTED: col'(k) = 4*(k&15) + (k>>4). Consistent on
// both write (P, VT) and read (A/B fragments), so PV result is unchanged
// (mod fp summation order). QK^T / masks use physical key index.
__device__ __forceinline__ void qk_mfma(const v8s qf[2], const char* Ks, int lo, int hi, v4f sa[4]){
#pragma unroll
  for (int st = 0; st < 4; ++st){
#pragma unroll
    for (int kc = 0; kc < 2; ++kc){
      v8s bf = *(const v8s*)(Ks + SWZ(st*16 + lo, kc*64 + hi*16));
      sa[st] = MFMA16(qf[kc], bf, sa[st]);
    }
  }
}

__device__ __forceinline__ void sm_pv(v4f sa[4], char* Pw, const char* VTs,
                                      int lo, int hi, float m[4], float l[4], v4f o[4]){
#pragma unroll
  for (int reg = 0; reg < 4; ++reg){
    float s0 = sa[0][reg], s1 = sa[1][reg], s2 = sa[2][reg], s3 = sa[3][reg];
    float tm = fmaxf(fmaxf(s0, s1), fmaxf(s2, s3));
    tm = fmaxf(tm, __shfl_xor(tm, 1));
    tm = fmaxf(tm, __shfl_xor(tm, 2));
    tm = fmaxf(tm, __shfl_xor(tm, 4));
    tm = fmaxf(tm, __shfl_xor(tm, 8));
    float mn = fmaxf(m[reg], tm);
    float corr = __expf(m[reg] - mn);
    m[reg] = mn;
    float p0 = __expf(s0 - mn), p1 = __expf(s1 - mn);
    float p2 = __expf(s2 - mn), p3 = __expf(s3 - mn);
    int qr = hi*4 + reg;
    uint2 ww;   // packed P row qr, cols' {4lo..4lo+3} (= physical keys st*16+lo)
    ww.x = (unsigned int)f2bf(p0) | ((unsigned int)f2bf(p1) << 16);
    ww.y = (unsigned int)f2bf(p2) | ((unsigned int)f2bf(p3) << 16);
    *(uint2*)(Pw + SWZ(qr, lo*8)) = ww;
    float ts = (p0 + p1) + (p2 + p3);
    ts += __shfl_xor(ts, 1);
    ts += __shfl_xor(ts, 2);
    ts += __shfl_xor(ts, 4);
    ts += __shfl_xor(ts, 8);
    l[reg] = l[reg] * corr + ts;
#pragma unroll
    for (int dt = 0; dt < 4; ++dt) o[dt][reg] *= corr;
  }
  asm volatile("" ::: "memory");
#pragma unroll
  for (int kc = 0; kc < 2; ++kc){
    v8s pa = *(const v8s*)(Pw + SWZ(lo, kc*64 + hi*16));
#pragma unroll
    for (int dt = 0; dt < 4; ++dt){
      v8s vbr = *(const v8s*)(VTs + SWZ(dt*16 + lo, kc*64 + hi*16));
      o[dt] = MFMA16(pa, vbr, o[dt]);
    }
  }
}

// ---------------- 4. diagonal causal (unfused: 1 q-tile/block, 4 waves) ----------------
__global__ __launch_bounds__(256) void diag_mfma(
    const ushort_t* __restrict__ qb, const ushort_t* __restrict__ kb, const ushort_t* __restrict__ vb,
    float* __restrict__ out, float* __restrict__ lse)
{
  __shared__ __align__(16) char Ks[8192];
  __shared__ __align__(16) char VTs[8192];
  __shared__ __align__(16) char Ps[4][2048];
  const int bid = blockIdx.x;              // 1024 = 8 xcd * 4 inst * 32 qt
  const int xcd = bid & 7, sl = bid >> 3;
  const int inst = xcd*4 + (sl >> 5);      // 4 instances per XCD (K/V L2-resident)
  const int qt = 31 - (sl & 31);           // long blocks dispatch first
  const int h = inst >> 2, tblk = inst & 3;
  const size_t hoff = (size_t)h * NSEQ * D;
  const ushort_t* qh = qb + hoff; const ushort_t* kh = kb + hoff; const ushort_t* vh = vb + hoff;
  const int blkbase = tblk * 2048;
  const int tid = threadIdx.x;
  const int w = tid >> 6, lane = tid & 63;
  const int lo = lane & 15, hi = lane >> 4;
  char* Pw = Ps[w];
  const int srow = tid & 63, spart = tid >> 6;        // K staging
  const int rp = tid & 31, cg = tid >> 5;             // VT staging
  const int vj0 = (rp & 15) + ((rp >> 4) << 5);       // key pair (vj0, vj0+16)
  const int vcolb = 8*(rp & 15) + 4*(rp >> 4);        // byte col' base

  v8s qf[2];
  {
    const ushort_t* r = qh + (size_t)(blkbase + qt*64 + w*16 + lo) * D;
    qf[0] = *(const v8s*)(r + hi*8);
    qf[1] = *(const v8s*)(r + 32 + hi*8);
  }
  const v4f vz = {0.0f, 0.0f, 0.0f, 0.0f};
  v4f o[4] = {vz, vz, vz, vz};
  float m[4] = {-INFINITY, -INFINITY, -INFINITY, -INFINITY};
  float l[4] = {0.0f, 0.0f, 0.0f, 0.0f};

#pragma unroll 1
  for (int kt = 0; kt <= qt; ++kt){
    __syncthreads();
    { // stage K tile
      const ushort_t* srcr = kh + (size_t)(blkbase + kt*64 + srow)*D + spart*16;
      uint4 a = *(const uint4*)srcr;
      uint4 b = *(const uint4*)(srcr + 8);
      *(uint4*)(Ks + SWZ(srow, spart*32)) = a;
      *(uint4*)(Ks + SWZ(srow, spart*32 + 16)) = b;
    }
    { // stage V transposed, key-pair (vj0, vj0+16) -> adjacent cols'
      const ushort_t* s0 = vh + (size_t)(blkbase + kt*64 + vj0)*D + cg*8;
      uint4 a0 = *(const uint4*)s0;
      uint4 a1 = *(const uint4*)(s0 + (size_t)16*D);
      const ushort_t* p0 = (const ushort_t*)&a0;
      const ushort_t* p1 = (const ushort_t*)&a1;
#pragma unroll
      for (int j = 0; j < 8; ++j){
        unsigned int pk = (unsigned int)p0[j] | ((unsigned int)p1[j] << 16);
        *(unsigned int*)(VTs + SWZ(cg*8 + j, vcolb)) = pk;
      }
    }
    __syncthreads();
    v4f sa[4] = {vz, vz, vz, vz};
    qk_mfma(qf, Ks, lo, hi, sa);
#pragma unroll
    for (int st = 0; st < 4; ++st) sa[st] *= SCALE;
    if (kt == qt){
#pragma unroll
      for (int st = 0; st < 4; ++st){
        int kpl = st*16 + lo;
#pragma unroll
        for (int reg = 0; reg < 4; ++reg)
          if (kpl > w*16 + hi*4 + reg) sa[st][reg] = -INFINITY;
      }
    }
    sm_pv(sa, Pw, VTs, lo, hi, m, l, o);
  }
#pragma unroll
  for (int reg = 0; reg < 4; ++reg){
    int rw = blkbase + qt*64 + w*16 + hi*4 + reg;
    float inv = 1.0f / l[reg];
#pragma unroll
    for (int dt = 0; dt < 4; ++dt)
      out[hoff + (size_t)rw*D + dt*16 + lo] = o[dt][reg] * inv;
    if (lo == 0) lse[h*NSEQ + rw] = m[reg] + logf(l[reg]);
  }
}

// ---------------- 5/6. LSH no-causal + merge (level 101 / 100), 4 waves ----------------
template<int LEVEL>
__global__ __launch_bounds__(256) void nc_mfma(
    const ushort_t* __restrict__ qb, const ushort_t* __restrict__ kb, const ushort_t* __restrict__ vb,
    float* __restrict__ out, float* __restrict__ lse,
    const int* __restrict__ qidx, const int* __restrict__ kidx, const int* __restrict__ samp)
{
  __shared__ __align__(16) char Ks[8192];
  __shared__ __align__(16) char VTs[8192];
  __shared__ __align__(16) char Ps[4][2048];
  __shared__ int kmk[64];
  const int bid = blockIdx.x;
  int inst, jb;
  if (LEVEL == 101){ int xcd = bid & 7, sl = bid >> 3; inst = xcd*2 + (sl >> 5); jb = sl & 31; }
  else             { inst = bid & 7; jb = bid >> 3; }
  const float delta = (LEVEL == 101) ? 2.0794415416798357f : 2.772588722239781f;
  const int seglen = (LEVEL == 101) ? 2048 : 4096;
  const int* qi = qidx + inst*seglen;
  const int* ki = kidx + inst*seglen;
  const int* sp = samp + inst*256;
  const int h = (LEVEL == 101) ? (inst >> 1) : inst;
  const int qblk = jb >> 2;
  const size_t hoff = (size_t)h * NSEQ * D;
  const ushort_t* qh = qb + hoff; const ushort_t* kh = kb + hoff; const ushort_t* vh = vb + hoff;
  const int tid = threadIdx.x;
  const int w = tid >> 6, lane = tid & 63;
  const int lo = lane & 15, hi = lane >> 4;
  char* Pw = Ps[w];
  const int srow = tid & 63, spart = tid >> 6;
  const int rp = tid & 31, cg = tid >> 5;
  const int vj0 = (rp & 15) + ((rp >> 4) << 5);
  const int vcolb = 8*(rp & 15) + 4*(rp >> 4);

  int orig[4];
  v8s qf[2];
  {
    int qrl = qi[jb*64 + w*16 + lo];
    const ushort_t* r = qh + (size_t)qrl * D;
    qf[0] = *(const v8s*)(r + hi*8);
    qf[1] = *(const v8s*)(r + 32 + hi*8);
#pragma unroll
    for (int reg = 0; reg < 4; ++reg) orig[reg] = qi[jb*64 + w*16 + hi*4 + reg];
  }
  const v4f vz = {0.0f, 0.0f, 0.0f, 0.0f};
  v4f o[4] = {vz, vz, vz, vz};
  float m[4] = {-INFINITY, -INFINITY, -INFINITY, -INFINITY};
  float l[4] = {0.0f, 0.0f, 0.0f, 0.0f};

#pragma unroll 1
  for (int kt = 0; kt < 8; ++kt){
    __syncthreads();
    { // stage K (gathered)
      int krow, msk = 0;
      if (kt < 4) krow = ki[qblk*256 + kt*64 + srow];
      else { int sidx = sp[(kt-4)*64 + srow]; krow = ki[sidx]; msk = ((sidx >> 8) == qblk) ? 1 : 0; }
      if (spart == 0) kmk[srow] = msk;
      const ushort_t* srcr = kh + (size_t)krow*D + spart*16;
      uint4 a = *(const uint4*)srcr;
      uint4 b = *(const uint4*)(srcr + 8);
      *(uint4*)(Ks + SWZ(srow, spart*32)) = a;
      *(uint4*)(Ks + SWZ(srow, spart*32 + 16)) = b;
    }
    { // stage VT (gathered, key-pair (vj0, vj0+16))
      int g0, g1;
      if (kt < 4){ g0 = ki[qblk*256 + kt*64 + vj0]; g1 = ki[qblk*256 + kt*64 + vj0 + 16]; }
      else       { g0 = ki[sp[(kt-4)*64 + vj0]];    g1 = ki[sp[(kt-4)*64 + vj0 + 16]]; }
      uint4 a0 = *(const uint4*)(vh + (size_t)g0*D + cg*8);
      uint4 a1 = *(const uint4*)(vh + (size_t)g1*D + cg*8);
      const ushort_t* p0 = (const ushort_t*)&a0;
      const ushort_t* p1 = (const ushort_t*)&a1;
#pragma unroll
      for (int j = 0; j < 8; ++j){
        unsigned int pk = (unsigned int)p0[j] | ((unsigned int)p1[j] << 16);
        *(unsigned int*)(VTs + SWZ(cg*8 + j, vcolb)) = pk;
      }
    }
    __syncthreads();
    v4f sa[4] = {vz, vz, vz, vz};
    qk_mfma(qf, Ks, lo, hi, sa);
    if (kt < 4){
#pragma unroll
      for (int st = 0; st < 4; ++st) sa[st] *= SCALE;
    } else {
      int km[4] = { kmk[lo], kmk[16+lo], kmk[32+lo], kmk[48+lo] };
#pragma unroll
      for (int st = 0; st < 4; ++st){
        if (km[st]) sa[st] = (v4f){-INFINITY, -INFINITY, -INFINITY, -INFINITY};
        else        sa[st] = sa[st]*SCALE + delta;
      }
    }
    sm_pv(sa, Pw, VTs, lo, hi, m, l, o);
  }
  // merge epilogue (_add_attn)
#pragma unroll
  for (int reg = 0; reg < 4; ++reg){
    int og = orig[reg];
    float l1v = lse[h*NSEQ + og];
    float l2v = m[reg] + logf(l[reg]);
    float c = 1.0f / (1.0f + __expf(l2v - l1v));
    float inv = (1.0f - c) / l[reg];
#pragma unroll
    for (int dt = 0; dt < 4; ++dt){
      float* ap = out + hoff + (size_t)og*D + dt*16 + lo;
      *ap = c * (*ap) + inv * o[dt][reg];
    }
    if (lo == 0) lse[h*NSEQ + og] = l1v - logf(c + EPSF);
  }
}

// ---------------- launch ----------------
extern "C" void kernel_launch(void* const* d_in, const int* in_sizes, int n_in,
                              void* d_out, int out_size, void* d_ws, size_t ws_size,
                              hipStream_t stream)
{
  const float* q    = (const float*)d_in[0];
  const float* k    = (const float*)d_in[1];
  const float* v    = (const float*)d_in[2];
  const float* proj = (const float*)d_in[3];
  float* out = (float*)d_out;

  char* ws = (char*)d_ws;
  float* lse = (float*)ws;                       // 256 KB
  int* hq   = (int*)(ws + 262144);               // 256 KB
  int* hk   = (int*)(ws + 524288);               // 256 KB
  int* q100 = (int*)(ws + 786432);               // 128 KB
  int* k100 = (int*)(ws + 917504);               // 128 KB
  int* q101 = (int*)(ws + 1048576);              // 128 KB
  int* k101 = (int*)(ws + 1179648);              // 128 KB
  int* s100 = (int*)(ws + 1310720);              // 8 KB
  int* s101 = (int*)(ws + 1318912);              // 16 KB
  ushort_t* qb = (ushort_t*)(ws + 1335296);      // 8 MB each
  ushort_t* kb = qb + (size_t)H*NSEQ*D;
  ushort_t* vb = kb + (size_t)H*NSEQ*D;

  prep_hash    <<<dim3(2048), dim3(256), 0, stream>>>(q, k, proj, qb, kb, hq, hk);
  prep_v       <<<dim3(2048), dim3(256), 0, stream>>>(v, vb);
  sample_kernel<<<dim3(24),   dim3(256), 0, stream>>>(s100, s101);
  sort_kernel  <<<dim3(48),   dim3(64),  0, stream>>>(hq, hk, q100, k100, q101, k101);
  diag_mfma    <<<dim3(1024), dim3(256), 0, stream>>>(qb, kb, vb, out, lse);
  nc_mfma<101> <<<dim3(512),  dim3(256), 0, stream>>>(qb, kb, vb, out, lse, q101, k101, s101);
  nc_mfma<100> <<<dim3(512),  dim3(256), 0, stream>>>(qb, kb, vb, out, lse, q100, k100, s100);
}

// Round 7
// 155.916 us; speedup vs baseline: 1.2607x; 1.2607x over previous
//
#include <hip/hip_runtime.h>
#include <stdint.h>
#include <math.h>

#define H 8
#define NSEQ 8192
#define D 64
#define SCALE 0.125f
#define EPSF 1.1920928955078125e-07f

typedef short v8s __attribute__((ext_vector_type(8)));
typedef float v4f __attribute__((ext_vector_type(4)));
typedef unsigned short ushort_t;

#define MFMA16(a,b,c) __builtin_amdgcn_mfma_f32_16x16x32_bf16((a),(b),(c),0,0,0)
// XOR bank swizzle (G4), 128B rows (K) and 256B rows (VT / P)
#define SWZ(row, cb)    (((row)*128) + ((cb) ^ ((((row)&7))<<4)))
#define SWZ256(row, cb) (((row)*256) + ((cb) ^ ((((row)&7))<<4)))

__device__ __forceinline__ ushort_t f2bf(float f){
  union { float f; unsigned int u; } c; c.f = f;
  unsigned int u = c.u + 0x7FFFu + ((c.u >> 16) & 1u);   // RNE
  return (ushort_t)(u >> 16);
}

// ---------------- 0a. fused prepass+hash for Q,K ----------------
__global__ __launch_bounds__(256) void prep_hash(
    const float* __restrict__ q, const float* __restrict__ k,
    const float* __restrict__ proj,
    ushort_t* __restrict__ qb, ushort_t* __restrict__ kb,
    int* __restrict__ hq, int* __restrict__ hk)
{
  __shared__ float tile[64][65];
  __shared__ float pj[448];
  const int bid = blockIdx.x;            // 2048 = 2 tensors x 1024 tiles
  const int isk = bid & 1;
  const int tix = bid >> 1;
  const int rowbase = tix << 6;
  const float* src = isk ? k : q;
  ushort_t* dstb = isk ? kb : qb;
  int* dsth = isk ? hk : hq;
  const int t = threadIdx.x;
  for (int i = t; i < 448; i += 256) pj[i] = proj[i];
  {
    const int r = t >> 2, cg = (t & 3) << 4;
    const float* s = src + (size_t)(rowbase + r)*64 + cg;
    float4 f0 = *(const float4*)(s);
    float4 f1 = *(const float4*)(s + 4);
    float4 f2 = *(const float4*)(s + 8);
    float4 f3 = *(const float4*)(s + 12);
    tile[r][cg+0]=f0.x;  tile[r][cg+1]=f0.y;  tile[r][cg+2]=f0.z;  tile[r][cg+3]=f0.w;
    tile[r][cg+4]=f1.x;  tile[r][cg+5]=f1.y;  tile[r][cg+6]=f1.z;  tile[r][cg+7]=f1.w;
    tile[r][cg+8]=f2.x;  tile[r][cg+9]=f2.y;  tile[r][cg+10]=f2.z; tile[r][cg+11]=f2.w;
    tile[r][cg+12]=f3.x; tile[r][cg+13]=f3.y; tile[r][cg+14]=f3.z; tile[r][cg+15]=f3.w;
    uint4 o0, o1;
    o0.x = (unsigned int)f2bf(f0.x) | ((unsigned int)f2bf(f0.y) << 16);
    o0.y = (unsigned int)f2bf(f0.z) | ((unsigned int)f2bf(f0.w) << 16);
    o0.z = (unsigned int)f2bf(f1.x) | ((unsigned int)f2bf(f1.y) << 16);
    o0.w = (unsigned int)f2bf(f1.z) | ((unsigned int)f2bf(f1.w) << 16);
    o1.x = (unsigned int)f2bf(f2.x) | ((unsigned int)f2bf(f2.y) << 16);
    o1.y = (unsigned int)f2bf(f2.z) | ((unsigned int)f2bf(f2.w) << 16);
    o1.z = (unsigned int)f2bf(f3.x) | ((unsigned int)f2bf(f3.y) << 16);
    o1.w = (unsigned int)f2bf(f3.z) | ((unsigned int)f2bf(f3.w) << 16);
    *(uint4*)(dstb + (size_t)(rowbase + r)*64 + cg) = o0;
    *(uint4*)(dstb + (size_t)(rowbase + r)*64 + cg + 8) = o1;
  }
  __syncthreads();
  if (t < 64){
    float dot[7] = {0,0,0,0,0,0,0};
    for (int d = 0; d < 64; ++d){      // EXACT serial fmaf order (hash stability)
      float x = tile[t][d];
#pragma unroll
      for (int p = 0; p < 7; ++p) dot[p] = fmaf(x, pj[d*7+p], dot[p]);
    }
    int b = 0;
#pragma unroll
    for (int p = 0; p < 7; ++p) if (dot[p] > 0.0f) b |= (1 << p);
    dsth[rowbase + t] = b ^ (b >> 1);
  }
}

// ---------------- 0b. bf16 prepass for V ----------------
__global__ __launch_bounds__(256) void prep_v(
    const float* __restrict__ v, ushort_t* __restrict__ vb)
{
  int gid = blockIdx.x * 256 + threadIdx.x;
  size_t off = (size_t)gid * 8;
  float4 f0 = *(const float4*)(v + off);
  float4 f1 = *(const float4*)(v + off + 4);
  uint4 o;
  o.x = (unsigned int)f2bf(f0.x) | ((unsigned int)f2bf(f0.y) << 16);
  o.y = (unsigned int)f2bf(f0.z) | ((unsigned int)f2bf(f0.w) << 16);
  o.z = (unsigned int)f2bf(f1.x) | ((unsigned int)f2bf(f1.y) << 16);
  o.w = (unsigned int)f2bf(f1.z) | ((unsigned int)f2bf(f1.w) << 16);
  *(uint4*)(vb + off) = o;
}

// ---------------- 2. Threefry-2x32-20 sampled indices (partitionable PRNG) ----------------
__device__ __forceinline__ void tf2x32(uint32_t k0, uint32_t k1,
                                       uint32_t x0, uint32_t x1,
                                       uint32_t& o0, uint32_t& o1)
{
  uint32_t ks0 = k0, ks1 = k1, ks2 = k0 ^ k1 ^ 0x1BD11BDAu;
  x0 += ks0; x1 += ks1;
#define RND(r) { x0 += x1; x1 = (x1 << (r)) | (x1 >> (32-(r))); x1 ^= x0; }
  RND(13) RND(15) RND(26) RND(6)  x0 += ks1; x1 += ks2 + 1u;
  RND(17) RND(29) RND(16) RND(24) x0 += ks2; x1 += ks0 + 2u;
  RND(13) RND(15) RND(26) RND(6)  x0 += ks0; x1 += ks1 + 3u;
  RND(17) RND(29) RND(16) RND(24) x0 += ks1; x1 += ks2 + 4u;
  RND(13) RND(15) RND(26) RND(6)  x0 += ks2; x1 += ks0 + 5u;
#undef RND
  o0 = x0; o1 = x1;
}

__global__ __launch_bounds__(256) void sample_kernel(int* __restrict__ s100, int* __restrict__ s101)
{
  int j = blockIdx.x * blockDim.x + threadIdx.x;
  int level, span, idx; int* out;
  if (j < 2048)      { level = 100; span = 4096; out = s100; idx = j; }
  else if (j < 6144) { level = 101; span = 2048; out = s101; idx = j - 2048; }
  else return;
  uint32_t r0, r1; tf2x32(0u, 42u, 0u, (uint32_t)level, r0, r1);
  uint32_t k20, k21; tf2x32(r0, r1, 0u, 1u, k20, k21);
  uint32_t o0, o1; tf2x32(k20, k21, 0u, (uint32_t)idx, o0, o1);
  uint32_t bits = o0 ^ o1;
  out[idx] = (int)(bits % (uint32_t)span);
}

// ---------------- 3. stable counting sort (128 threads) ----------------
__global__ __launch_bounds__(128) void sort_kernel(
    const int* __restrict__ hq, const int* __restrict__ hk,
    int* __restrict__ q100, int* __restrict__ k100,
    int* __restrict__ q101, int* __restrict__ k101)
{
  __shared__ unsigned short hist[128][128];
  __shared__ unsigned short off [128][128];
  __shared__ int bstart[128];
  const int bid = blockIdx.x, t = threadIdx.x;
  const int* src; int n, base; int* out;
  if (bid < 8)       { int h = bid;     src = hq + h*NSEQ + 4096;          n = 4096; base = 4096;          out = q100 + h*4096; }
  else if (bid < 16) { int h = bid - 8; src = hk + h*NSEQ;                 n = 4096; base = 0;             out = k100 + h*4096; }
  else if (bid < 32) { int id = bid-16; int h = id>>1, p = id&1;
                       src = hq + h*NSEQ + p*4096 + 2048;                  n = 2048; base = p*4096 + 2048; out = q101 + id*2048; }
  else               { int id = bid-32; int h = id>>1, p = id&1;
                       src = hk + h*NSEQ + p*4096;                         n = 2048; base = p*4096;       out = k101 + id*2048; }
  const int chunk = n >> 7;
  for (int b = 0; b < 128; ++b) hist[t][b] = 0;
  __syncthreads();
  const int* mysrc = src + t * chunk;
  for (int i = 0; i < chunk; ++i) hist[t][mysrc[i]]++;
  __syncthreads();
  {
    int s = 0;
    for (int tt = 0; tt < 128; ++tt) s += hist[tt][t];
    bstart[t] = s;
  }
  __syncthreads();
  if (t == 0){
    int run = 0;
    for (int b = 0; b < 128; ++b){ int c = bstart[b]; bstart[b] = run; run += c; }
  }
  __syncthreads();
  {
    unsigned int run = (unsigned int)bstart[t];
    for (int tt = 0; tt < 128; ++tt){ off[tt][t] = (unsigned short)run; run += hist[tt][t]; }
  }
  __syncthreads();
  for (int i = 0; i < chunk; ++i){
    int hsh = mysrc[i];
    unsigned short pos = off[t][hsh]++;
    out[pos] = base + t * chunk + i;
  }
}

// ================= shared MFMA flash helpers (KVBLK=128) =================
// Key axis in P/VT permuted: col'(k) = 8*(k&15) + (k>>4), consistent on both
// sides of PV -> contraction reordered only. QK^T/masks use physical k.
__device__ __forceinline__ void qk8(const v8s qf[2], const char* Ks, int lo, int hi, v4f sa[8]){
#pragma unroll
  for (int st = 0; st < 8; ++st){
#pragma unroll
    for (int kc = 0; kc < 2; ++kc){
      v8s bf = *(const v8s*)(Ks + SWZ(st*16 + lo, kc*64 + hi*16));
      sa[st] = MFMA16(qf[kc], bf, sa[st]);
    }
  }
}

__device__ __forceinline__ void sm_pv8(v4f sa[8], char* Pw, const char* VTs,
                                       int lo, int hi, float m[4], float l[4], v4f o[4]){
#pragma unroll
  for (int reg = 0; reg < 4; ++reg){
    float tm = fmaxf(fmaxf(fmaxf(sa[0][reg], sa[1][reg]), fmaxf(sa[2][reg], sa[3][reg])),
                     fmaxf(fmaxf(sa[4][reg], sa[5][reg]), fmaxf(sa[6][reg], sa[7][reg])));
    tm = fmaxf(tm, __shfl_xor(tm, 1));
    tm = fmaxf(tm, __shfl_xor(tm, 2));
    tm = fmaxf(tm, __shfl_xor(tm, 4));
    tm = fmaxf(tm, __shfl_xor(tm, 8));
    float mn = fmaxf(m[reg], tm);
    float corr = __expf(m[reg] - mn);
    m[reg] = mn;
    float p[8];
    float ts = 0.0f;
#pragma unroll
    for (int st = 0; st < 8; ++st){ p[st] = __expf(sa[st][reg] - mn); ts += p[st]; }
    uint4 pw;
    pw.x = (unsigned int)f2bf(p[0]) | ((unsigned int)f2bf(p[1]) << 16);
    pw.y = (unsigned int)f2bf(p[2]) | ((unsigned int)f2bf(p[3]) << 16);
    pw.z = (unsigned int)f2bf(p[4]) | ((unsigned int)f2bf(p[5]) << 16);
    pw.w = (unsigned int)f2bf(p[6]) | ((unsigned int)f2bf(p[7]) << 16);
    *(uint4*)(Pw + SWZ256(hi*4 + reg, 16*lo)) = pw;
    ts += __shfl_xor(ts, 1);
    ts += __shfl_xor(ts, 2);
    ts += __shfl_xor(ts, 4);
    ts += __shfl_xor(ts, 8);
    l[reg] = l[reg] * corr + ts;
#pragma unroll
    for (int dt = 0; dt < 4; ++dt) o[dt][reg] *= corr;
  }
  asm volatile("" ::: "memory");   // order P writes before PV reads (same wave)
#pragma unroll
  for (int kb = 0; kb < 4; ++kb){
    v8s pa = *(const v8s*)(Pw + SWZ256(lo, kb*64 + hi*16));
#pragma unroll
    for (int dt = 0; dt < 4; ++dt){
      v8s vbr = *(const v8s*)(VTs + SWZ256(dt*16 + lo, kb*64 + hi*16));
      o[dt] = MFMA16(pa, vbr, o[dt]);
    }
  }
}

// V-stage repack: 4 keys' d-slices -> VT col'-packed uint2 per d
__device__ __forceinline__ void vt_write(char* VTs, uint2 vr0, uint2 vr1, uint2 vr2, uint2 vr3,
                                         int vdg, int vlo, int vsth){
  const int cb = 16*vlo + vsth*8;
  uint2 w;
  w.x = (vr0.x & 0xFFFFu) | ((vr1.x & 0xFFFFu) << 16);
  w.y = (vr2.x & 0xFFFFu) | ((vr3.x & 0xFFFFu) << 16);
  *(uint2*)(VTs + SWZ256(vdg*4 + 0, cb)) = w;
  w.x = (vr0.x >> 16) | (vr1.x & 0xFFFF0000u);
  w.y = (vr2.x >> 16) | (vr3.x & 0xFFFF0000u);
  *(uint2*)(VTs + SWZ256(vdg*4 + 1, cb)) = w;
  w.x = (vr0.y & 0xFFFFu) | ((vr1.y & 0xFFFFu) << 16);
  w.y = (vr2.y & 0xFFFFu) | ((vr3.y & 0xFFFFu) << 16);
  *(uint2*)(VTs + SWZ256(vdg*4 + 2, cb)) = w;
  w.x = (vr0.y >> 16) | (vr1.y & 0xFFFF0000u);
  w.y = (vr2.y >> 16) | (vr3.y & 0xFFFF0000u);
  *(uint2*)(VTs + SWZ256(vdg*4 + 3, cb)) = w;
}

// ---------------- 4. diagonal causal (fused pair, 8 waves, KVBLK=128) ----------------
__global__ __launch_bounds__(512, 4) void diag_mfma(
    const ushort_t* __restrict__ qb, const ushort_t* __restrict__ kb, const ushort_t* __restrict__ vb,
    float* __restrict__ out, float* __restrict__ lse)
{
  __shared__ __align__(16) char Ks[16384];    // [128 key][64 d]
  __shared__ __align__(16) char VTs[16384];   // [64 d][128 col']
  __shared__ __align__(16) char Ps[8][4096];  // per wave [16 q][128 col']
  const int bid = blockIdx.x;                 // 512 = 8 xcd * 4 inst * 16 pairs
  const int xcd = bid & 7, sl = bid >> 3;
  const int inst = xcd*4 + (sl >> 4);
  const int pi = sl & 15;
  const int h = inst >> 2, tblk = inst & 3;
  const size_t hoff = (size_t)h * NSEQ * D;
  const ushort_t* qh = qb + hoff; const ushort_t* kh = kb + hoff; const ushort_t* vh = vb + hoff;
  const int blkbase = tblk * 2048;
  const int tid = threadIdx.x;
  const int w = tid >> 6, lane = tid & 63;
  const int lo = lane & 15, hi = lane >> 4;
  char* Pw = Ps[w];
  // staging maps (512 threads): K row = 4 threads x 32B (full 128B row)
  const int kr = tid >> 2, kq = tid & 3;
  const int vlo = tid & 15, vdg = (tid >> 4) & 15, vsth = tid >> 8;

  const int qt  = (w < 4) ? (31 - pi) : pi;                 // waves 0-3: long tile
  const int wq  = w & 3;                                    // 16-row group in tile
  const int nkt   = (31 - pi)/2 + 1;                        // loop length (long tile)
  const int mynkt = qt/2 + 1;                               // this wave's tiles
  const int qpos0 = qt*64 + wq*16;

  v8s qf[2];
  {
    const ushort_t* r = qh + (size_t)(blkbase + qpos0 + lo) * D;
    qf[0] = *(const v8s*)(r + hi*8);
    qf[1] = *(const v8s*)(r + 32 + hi*8);
  }
  const v4f vz = {0.0f, 0.0f, 0.0f, 0.0f};
  v4f o[4] = {vz, vz, vz, vz};
  float m[4] = {-INFINITY, -INFINITY, -INFINITY, -INFINITY};
  float l[4] = {0.0f, 0.0f, 0.0f, 0.0f};

  uint4 kreg0, kreg1; uint2 vr0, vr1, vr2, vr3;
#define DLOAD(kt) { \
    const ushort_t* ksr = kh + (size_t)(blkbase + (kt)*128 + kr)*D + kq*16; \
    kreg0 = *(const uint4*)ksr; \
    kreg1 = *(const uint4*)(ksr + 8); \
    const ushort_t* vs = vh + (size_t)(blkbase + (kt)*128 + vsth*64 + vlo)*D + vdg*4; \
    vr0 = *(const uint2*)(vs); \
    vr1 = *(const uint2*)(vs + 16*D); \
    vr2 = *(const uint2*)(vs + 32*D); \
    vr3 = *(const uint2*)(vs + 48*D); }

  DLOAD(0);
#pragma unroll 1
  for (int kt = 0; kt < nkt; ++kt){
    *(uint4*)(Ks + SWZ(kr, kq*32))      = kreg0;
    *(uint4*)(Ks + SWZ(kr, kq*32 + 16)) = kreg1;
    vt_write(VTs, vr0, vr1, vr2, vr3, vdg, vlo, vsth);
    __syncthreads();
    if (kt + 1 < nkt) DLOAD(kt+1);
    if (kt < mynkt){
      v4f sa[8] = {vz, vz, vz, vz, vz, vz, vz, vz};
      qk8(qf, Ks, lo, hi, sa);
#pragma unroll
      for (int st = 0; st < 8; ++st) sa[st] *= SCALE;
      if (kt == mynkt - 1){
#pragma unroll
        for (int st = 0; st < 8; ++st){
          int kpos = kt*128 + st*16 + lo;
#pragma unroll
          for (int reg = 0; reg < 4; ++reg)
            if (kpos > qpos0 + hi*4 + reg) sa[st][reg] = -INFINITY;
        }
      }
      sm_pv8(sa, Pw, VTs, lo, hi, m, l, o);
    }
    __syncthreads();
  }
#undef DLOAD
#pragma unroll
  for (int reg = 0; reg < 4; ++reg){
    int rw = blkbase + qpos0 + hi*4 + reg;
    float inv = 1.0f / l[reg];
#pragma unroll
    for (int dt = 0; dt < 4; ++dt)
      out[hoff + (size_t)rw*D + dt*16 + lo] = o[dt][reg] * inv;
    if (lo == 0) lse[h*NSEQ + rw] = m[reg] + logf(l[reg]);
  }
}

// ---------------- 5/6. LSH no-causal + merge, 8 waves, KVBLK=128 ----------------
__device__ __forceinline__ int nc_key(const int* __restrict__ ki, const int* __restrict__ sp,
                                      int qblk, int kt, int pos, int& msk){
  if (kt < 2){ msk = 0; return ki[qblk*256 + kt*128 + pos]; }
  int s = sp[(kt-2)*128 + pos]; msk = ((s >> 8) == qblk) ? 1 : 0; return ki[s];
}

template<int LEVEL>
__global__ __launch_bounds__(512, 4) void nc_mfma(
    const ushort_t* __restrict__ qb, const ushort_t* __restrict__ kb, const ushort_t* __restrict__ vb,
    float* __restrict__ out, float* __restrict__ lse,
    const int* __restrict__ qidx, const int* __restrict__ kidx, const int* __restrict__ samp)
{
  __shared__ __align__(16) char Ks[16384];
  __shared__ __align__(16) char VTs[16384];
  __shared__ __align__(16) char Ps[8][4096];
  __shared__ int kmk[128];
  const int bid = blockIdx.x;
  int inst, jb;
  if (LEVEL == 101){ int xcd = bid & 7, sl = bid >> 3; inst = xcd*2 + (sl >> 4); jb = sl & 15; }
  else             { inst = bid & 7; jb = bid >> 3; }
  const float delta = (LEVEL == 101) ? 2.0794415416798357f : 2.772588722239781f;
  const int seglen = (LEVEL == 101) ? 2048 : 4096;
  const int* qi = qidx + inst*seglen;
  const int* ki = kidx + inst*seglen;
  const int* sp = samp + inst*256;
  const int h = (LEVEL == 101) ? (inst >> 1) : inst;
  const int qblk = jb >> 1;                   // sorted 256-block of this 128-row group
  const size_t hoff = (size_t)h * NSEQ * D;
  const ushort_t* qh = qb + hoff; const ushort_t* kh = kb + hoff; const ushort_t* vh = vb + hoff;
  const int tid = threadIdx.x;
  const int w = tid >> 6, lane = tid & 63;
  const int lo = lane & 15, hi = lane >> 4;
  char* Pw = Ps[w];
  const int kr = tid >> 2, kq = tid & 3;
  const int vlo = tid & 15, vdg = (tid >> 4) & 15, vsth = tid >> 8;

  int orig[4];
  v8s qf[2];
  {
    int qrl = qi[jb*128 + w*16 + lo];
    const ushort_t* r = qh + (size_t)qrl * D;
    qf[0] = *(const v8s*)(r + hi*8);
    qf[1] = *(const v8s*)(r + 32 + hi*8);
#pragma unroll
    for (int reg = 0; reg < 4; ++reg) orig[reg] = qi[jb*128 + w*16 + hi*4 + reg];
  }
  const v4f vz = {0.0f, 0.0f, 0.0f, 0.0f};
  v4f o[4] = {vz, vz, vz, vz};
  float m[4] = {-INFINITY, -INFINITY, -INFINITY, -INFINITY};
  float l[4] = {0.0f, 0.0f, 0.0f, 0.0f};

  uint4 kreg0, kreg1; uint2 vr0, vr1, vr2, vr3; int msk;
#define NLOAD(kt) { \
    int krow = nc_key(ki, sp, qblk, kt, kr, msk); \
    const ushort_t* ksr = kh + (size_t)krow*D + kq*16; \
    kreg0 = *(const uint4*)ksr; \
    kreg1 = *(const uint4*)(ksr + 8); \
    int m_; \
    int g0 = nc_key(ki, sp, qblk, kt, vsth*64 + vlo,      m_); \
    int g1 = nc_key(ki, sp, qblk, kt, vsth*64 + 16 + vlo, m_); \
    int g2 = nc_key(ki, sp, qblk, kt, vsth*64 + 32 + vlo, m_); \
    int g3 = nc_key(ki, sp, qblk, kt, vsth*64 + 48 + vlo, m_); \
    vr0 = *(const uint2*)(vh + (size_t)g0*D + vdg*4); \
    vr1 = *(const uint2*)(vh + (size_t)g1*D + vdg*4); \
    vr2 = *(const uint2*)(vh + (size_t)g2*D + vdg*4); \
    vr3 = *(const uint2*)(vh + (size_t)g3*D + vdg*4); }

  NLOAD(0);
#pragma unroll 1
  for (int kt = 0; kt < 4; ++kt){
    *(uint4*)(Ks + SWZ(kr, kq*32))      = kreg0;
    *(uint4*)(Ks + SWZ(kr, kq*32 + 16)) = kreg1;
    if (kq == 0) kmk[kr] = msk;
    vt_write(VTs, vr0, vr1, vr2, vr3, vdg, vlo, vsth);
    __syncthreads();
    if (kt + 1 < 4) NLOAD(kt+1);
    v4f sa[8] = {vz, vz, vz, vz, vz, vz, vz, vz};
    qk8(qf, Ks, lo, hi, sa);
    if (kt < 2){
#pragma unroll
      for (int st = 0; st < 8; ++st) sa[st] *= SCALE;
    } else {
#pragma unroll
      for (int st = 0; st < 8; ++st){
        if (kmk[st*16 + lo]) sa[st] = (v4f){-INFINITY, -INFINITY, -INFINITY, -INFINITY};
        else                 sa[st] = sa[st]*SCALE + delta;
      }
    }
    sm_pv8(sa, Pw, VTs, lo, hi, m, l, o);
    __syncthreads();
  }
#undef NLOAD
  // merge epilogue (_add_attn)
#pragma unroll
  for (int reg = 0; reg < 4; ++reg){
    int og = orig[reg];
    float l1v = lse[h*NSEQ + og];
    float l2v = m[reg] + logf(l[reg]);
    float c = 1.0f / (1.0f + __expf(l2v - l1v));
    float inv = (1.0f - c) / l[reg];
#pragma unroll
    for (int dt = 0; dt < 4; ++dt){
      float* ap = out + hoff + (size_t)og*D + dt*16 + lo;
      *ap = c * (*ap) + inv * o[dt][reg];
    }
    if (lo == 0) lse[h*NSEQ + og] = l1v - logf(c + EPSF);
  }
}

// ---------------- launch ----------------
extern "C" void kernel_launch(void* const* d_in, const int* in_sizes, int n_in,
                              void* d_out, int out_size, void* d_ws, size_t ws_size,
                              hipStream_t stream)
{
  const float* q    = (const float*)d_in[0];
  const float* k    = (const float*)d_in[1];
  const float* v    = (const float*)d_in[2];
  const float* proj = (const float*)d_in[3];
  float* out = (float*)d_out;

  char* ws = (char*)d_ws;
  float* lse = (float*)ws;                       // 256 KB
  int* hq   = (int*)(ws + 262144);               // 256 KB
  int* hk   = (int*)(ws + 524288);               // 256 KB
  int* q100 = (int*)(ws + 786432);               // 128 KB
  int* k100 = (int*)(ws + 917504);               // 128 KB
  int* q101 = (int*)(ws + 1048576);              // 128 KB
  int* k101 = (int*)(ws + 1179648);              // 128 KB
  int* s100 = (int*)(ws + 1310720);              // 8 KB
  int* s101 = (int*)(ws + 1318912);              // 16 KB
  ushort_t* qb = (ushort_t*)(ws + 1335296);      // 8 MB each
  ushort_t* kb = qb + (size_t)H*NSEQ*D;
  ushort_t* vb = kb + (size_t)H*NSEQ*D;

  prep_hash    <<<dim3(2048), dim3(256), 0, stream>>>(q, k, proj, qb, kb, hq, hk);
  prep_v       <<<dim3(2048), dim3(256), 0, stream>>>(v, vb);
  sample_kernel<<<dim3(24),   dim3(256), 0, stream>>>(s100, s101);
  sort_kernel  <<<dim3(48),   dim3(128), 0, stream>>>(hq, hk, q100, k100, q101, k101);
  diag_mfma    <<<dim3(512),  dim3(512), 0, stream>>>(qb, kb, vb, out, lse);
  nc_mfma<101> <<<dim3(256),  dim3(512), 0, stream>>>(qb, kb, vb, out, lse, q101, k101, s101);
  nc_mfma<100> <<<dim3(256),  dim3(512), 0, stream>>>(qb, kb, vb, out, lse, q100, k100, s100);
}

// Round 8
// 129.356 us; speedup vs baseline: 1.5196x; 1.2053x over previous
//
#include <hip/hip_runtime.h>
#include <stdint.h>
#include <math.h>

#define H 8
#define NSEQ 8192
#define D 64
// score scale folded into log2 domain: 1/sqrt(64) * log2(e)
#define SC2 0.18033688011112042f
#define LN2F 0.69314718055994531f
#define THR2 10.0f
#define EPSF 1.1920928955078125e-07f

typedef short v8s __attribute__((ext_vector_type(8)));
typedef float v4f __attribute__((ext_vector_type(4)));
typedef unsigned short ushort_t;

#define MFMA16(a,b,c) __builtin_amdgcn_mfma_f32_16x16x32_bf16((a),(b),(c),0,0,0)
// XOR bank swizzle (G4), 128B rows (K) and 256B rows (VT / P)
#define SWZ(row, cb)    (((row)*128) + ((cb) ^ ((((row)&7))<<4)))
#define SWZ256(row, cb) (((row)*256) + ((cb) ^ ((((row)&7))<<4)))

__device__ __forceinline__ ushort_t f2bf(float f){
  union { float f; unsigned int u; } c; c.f = f;
  unsigned int u = c.u + 0x7FFFu + ((c.u >> 16) & 1u);   // RNE
  return (ushort_t)(u >> 16);
}
__device__ __forceinline__ float exp2x(float x){         // raw v_exp_f32 (2^x)
  float r; asm("v_exp_f32 %0, %1" : "=v"(r) : "v"(x)); return r;
}
__device__ __forceinline__ unsigned int cvtpk(float a, float b){ // 2xf32 -> packed bf16
  unsigned int r; asm("v_cvt_pk_bf16_f32 %0, %1, %2" : "=v"(r) : "v"(a), "v"(b)); return r;
}

// ---------------- 0a. fused prepass+hash for Q,K ----------------
__global__ __launch_bounds__(256) void prep_hash(
    const float* __restrict__ q, const float* __restrict__ k,
    const float* __restrict__ proj,
    ushort_t* __restrict__ qb, ushort_t* __restrict__ kb,
    int* __restrict__ hq, int* __restrict__ hk)
{
  __shared__ float tile[64][65];
  __shared__ float pj[448];
  const int bid = blockIdx.x;            // 2048 = 2 tensors x 1024 tiles
  const int isk = bid & 1;
  const int tix = bid >> 1;
  const int rowbase = tix << 6;
  const float* src = isk ? k : q;
  ushort_t* dstb = isk ? kb : qb;
  int* dsth = isk ? hk : hq;
  const int t = threadIdx.x;
  for (int i = t; i < 448; i += 256) pj[i] = proj[i];
  {
    const int r = t >> 2, cg = (t & 3) << 4;
    const float* s = src + (size_t)(rowbase + r)*64 + cg;
    float4 f0 = *(const float4*)(s);
    float4 f1 = *(const float4*)(s + 4);
    float4 f2 = *(const float4*)(s + 8);
    float4 f3 = *(const float4*)(s + 12);
    tile[r][cg+0]=f0.x;  tile[r][cg+1]=f0.y;  tile[r][cg+2]=f0.z;  tile[r][cg+3]=f0.w;
    tile[r][cg+4]=f1.x;  tile[r][cg+5]=f1.y;  tile[r][cg+6]=f1.z;  tile[r][cg+7]=f1.w;
    tile[r][cg+8]=f2.x;  tile[r][cg+9]=f2.y;  tile[r][cg+10]=f2.z; tile[r][cg+11]=f2.w;
    tile[r][cg+12]=f3.x; tile[r][cg+13]=f3.y; tile[r][cg+14]=f3.z; tile[r][cg+15]=f3.w;
    uint4 o0, o1;
    o0.x = cvtpk(f0.x, f0.y);  o0.y = cvtpk(f0.z, f0.w);
    o0.z = cvtpk(f1.x, f1.y);  o0.w = cvtpk(f1.z, f1.w);
    o1.x = cvtpk(f2.x, f2.y);  o1.y = cvtpk(f2.z, f2.w);
    o1.z = cvtpk(f3.x, f3.y);  o1.w = cvtpk(f3.z, f3.w);
    *(uint4*)(dstb + (size_t)(rowbase + r)*64 + cg) = o0;
    *(uint4*)(dstb + (size_t)(rowbase + r)*64 + cg + 8) = o1;
  }
  __syncthreads();
  if (t < 64){
    float dot[7] = {0,0,0,0,0,0,0};
    for (int d = 0; d < 64; ++d){      // EXACT serial fmaf order (hash stability)
      float x = tile[t][d];
#pragma unroll
      for (int p = 0; p < 7; ++p) dot[p] = fmaf(x, pj[d*7+p], dot[p]);
    }
    int b = 0;
#pragma unroll
    for (int p = 0; p < 7; ++p) if (dot[p] > 0.0f) b |= (1 << p);
    dsth[rowbase + t] = b ^ (b >> 1);
  }
}

// ---------------- 0b. bf16 prepass for V ----------------
__global__ __launch_bounds__(256) void prep_v(
    const float* __restrict__ v, ushort_t* __restrict__ vb)
{
  int gid = blockIdx.x * 256 + threadIdx.x;
  size_t off = (size_t)gid * 8;
  float4 f0 = *(const float4*)(v + off);
  float4 f1 = *(const float4*)(v + off + 4);
  uint4 o;
  o.x = cvtpk(f0.x, f0.y);  o.y = cvtpk(f0.z, f0.w);
  o.z = cvtpk(f1.x, f1.y);  o.w = cvtpk(f1.z, f1.w);
  *(uint4*)(vb + off) = o;
}

// ---------------- 2. Threefry-2x32-20 sampled indices (partitionable PRNG) ----------------
__device__ __forceinline__ void tf2x32(uint32_t k0, uint32_t k1,
                                       uint32_t x0, uint32_t x1,
                                       uint32_t& o0, uint32_t& o1)
{
  uint32_t ks0 = k0, ks1 = k1, ks2 = k0 ^ k1 ^ 0x1BD11BDAu;
  x0 += ks0; x1 += ks1;
#define RND(r) { x0 += x1; x1 = (x1 << (r)) | (x1 >> (32-(r))); x1 ^= x0; }
  RND(13) RND(15) RND(26) RND(6)  x0 += ks1; x1 += ks2 + 1u;
  RND(17) RND(29) RND(16) RND(24) x0 += ks2; x1 += ks0 + 2u;
  RND(13) RND(15) RND(26) RND(6)  x0 += ks0; x1 += ks1 + 3u;
  RND(17) RND(29) RND(16) RND(24) x0 += ks1; x1 += ks2 + 4u;
  RND(13) RND(15) RND(26) RND(6)  x0 += ks2; x1 += ks0 + 5u;
#undef RND
  o0 = x0; o1 = x1;
}

__global__ __launch_bounds__(256) void sample_kernel(int* __restrict__ s100, int* __restrict__ s101)
{
  int j = blockIdx.x * blockDim.x + threadIdx.x;
  int level, span, idx; int* out;
  if (j < 2048)      { level = 100; span = 4096; out = s100; idx = j; }
  else if (j < 6144) { level = 101; span = 2048; out = s101; idx = j - 2048; }
  else return;
  uint32_t r0, r1; tf2x32(0u, 42u, 0u, (uint32_t)level, r0, r1);
  uint32_t k20, k21; tf2x32(r0, r1, 0u, 1u, k20, k21);
  uint32_t o0, o1; tf2x32(k20, k21, 0u, (uint32_t)idx, o0, o1);
  uint32_t bits = o0 ^ o1;
  out[idx] = (int)(bits % (uint32_t)span);
}

// ---------------- 3. stable counting sort (128 threads) ----------------
__global__ __launch_bounds__(128) void sort_kernel(
    const int* __restrict__ hq, const int* __restrict__ hk,
    int* __restrict__ q100, int* __restrict__ k100,
    int* __restrict__ q101, int* __restrict__ k101)
{
  __shared__ unsigned short hist[128][128];
  __shared__ unsigned short off [128][128];
  __shared__ int bstart[128];
  const int bid = blockIdx.x, t = threadIdx.x;
  const int* src; int n, base; int* out;
  if (bid < 8)       { int h = bid;     src = hq + h*NSEQ + 4096;          n = 4096; base = 4096;          out = q100 + h*4096; }
  else if (bid < 16) { int h = bid - 8; src = hk + h*NSEQ;                 n = 4096; base = 0;             out = k100 + h*4096; }
  else if (bid < 32) { int id = bid-16; int h = id>>1, p = id&1;
                       src = hq + h*NSEQ + p*4096 + 2048;                  n = 2048; base = p*4096 + 2048; out = q101 + id*2048; }
  else               { int id = bid-32; int h = id>>1, p = id&1;
                       src = hk + h*NSEQ + p*4096;                         n = 2048; base = p*4096;       out = k101 + id*2048; }
  const int chunk = n >> 7;
  for (int b = 0; b < 128; ++b) hist[t][b] = 0;
  __syncthreads();
  const int* mysrc = src + t * chunk;
  for (int i = 0; i < chunk; ++i) hist[t][mysrc[i]]++;
  __syncthreads();
  {
    int s = 0;
    for (int tt = 0; tt < 128; ++tt) s += hist[tt][t];
    bstart[t] = s;
  }
  __syncthreads();
  if (t == 0){
    int run = 0;
    for (int b = 0; b < 128; ++b){ int c = bstart[b]; bstart[b] = run; run += c; }
  }
  __syncthreads();
  {
    unsigned int run = (unsigned int)bstart[t];
    for (int tt = 0; tt < 128; ++tt){ off[tt][t] = (unsigned short)run; run += hist[tt][t]; }
  }
  __syncthreads();
  for (int i = 0; i < chunk; ++i){
    int hsh = mysrc[i];
    unsigned short pos = off[t][hsh]++;
    out[pos] = base + t * chunk + i;
  }
}

// ================= shared MFMA flash helpers (KVBLK=128) =================
// Key axis in P/VT permuted: col'(k) = 8*(k&15) + (k>>4), consistent on both
// sides of PV -> contraction reordered only. QK^T/masks use physical k.
// o[0..3] = P.V  d-tiles; o[4] = P.1 (softmax denominator via ones-column).
__device__ __forceinline__ void qk8(const v8s qf[2], const char* Ks, int lo, int hi, v4f sa[8]){
  __builtin_amdgcn_s_setprio(1);
#pragma unroll
  for (int st = 0; st < 8; ++st){
#pragma unroll
    for (int kc = 0; kc < 2; ++kc){
      v8s bf = *(const v8s*)(Ks + SWZ(st*16 + lo, kc*64 + hi*16));
      sa[st] = MFMA16(qf[kc], bf, sa[st]);
    }
  }
  __builtin_amdgcn_s_setprio(0);
}

__device__ __forceinline__ void sm_pv8(v4f sa[8], char* Pw, const char* VTs,
                                       int lo, int hi, float m[4], v4f o[5]){
  // scores are in log2 domain. defer-max (T13): only shfl-reduce + rescale on growth.
  float tm[4];
  bool grow = false;
#pragma unroll
  for (int reg = 0; reg < 4; ++reg){
    float a = fmaxf(fmaxf(sa[0][reg], sa[1][reg]), fmaxf(sa[2][reg], sa[3][reg]));
    float b = fmaxf(fmaxf(sa[4][reg], sa[5][reg]), fmaxf(sa[6][reg], sa[7][reg]));
    tm[reg] = fmaxf(a, b);
    grow = grow || (tm[reg] > m[reg] + THR2);
  }
  if (__any(grow)){
#pragma unroll
    for (int reg = 0; reg < 4; ++reg){
      float t = tm[reg];
      t = fmaxf(t, __shfl_xor(t, 1));
      t = fmaxf(t, __shfl_xor(t, 2));
      t = fmaxf(t, __shfl_xor(t, 4));
      t = fmaxf(t, __shfl_xor(t, 8));
      float mn = fmaxf(m[reg], t);
      float corr = exp2x(m[reg] - mn);
      m[reg] = mn;
#pragma unroll
      for (int dt = 0; dt < 5; ++dt) o[dt][reg] *= corr;
    }
  }
#pragma unroll
  for (int reg = 0; reg < 4; ++reg){
    float mr = m[reg];
    uint4 pw;
    pw.x = cvtpk(exp2x(sa[0][reg]-mr), exp2x(sa[1][reg]-mr));
    pw.y = cvtpk(exp2x(sa[2][reg]-mr), exp2x(sa[3][reg]-mr));
    pw.z = cvtpk(exp2x(sa[4][reg]-mr), exp2x(sa[5][reg]-mr));
    pw.w = cvtpk(exp2x(sa[6][reg]-mr), exp2x(sa[7][reg]-mr));
    *(uint4*)(Pw + SWZ256(hi*4 + reg, 16*lo)) = pw;
  }
  asm volatile("" ::: "memory");   // order P writes before PV reads (same wave)
  __builtin_amdgcn_s_setprio(1);
#pragma unroll
  for (int kb = 0; kb < 4; ++kb){
    v8s pa = *(const v8s*)(Pw + SWZ256(lo, kb*64 + hi*16));
#pragma unroll
    for (int dt = 0; dt < 5; ++dt){
      v8s vbr = *(const v8s*)(VTs + SWZ256(dt*16 + lo, kb*64 + hi*16));
      o[dt] = MFMA16(pa, vbr, o[dt]);
    }
  }
  __builtin_amdgcn_s_setprio(0);
}

// V-stage repack: 4 keys' d-slices -> VT col'-packed uint2 per d
__device__ __forceinline__ void vt_write(char* VTs, uint2 vr0, uint2 vr1, uint2 vr2, uint2 vr3,
                                         int vdg, int vlo, int vsth){
  const int cb = 16*vlo + vsth*8;
  uint2 w;
  w.x = (vr0.x & 0xFFFFu) | ((vr1.x & 0xFFFFu) << 16);
  w.y = (vr2.x & 0xFFFFu) | ((vr3.x & 0xFFFFu) << 16);
  *(uint2*)(VTs + SWZ256(vdg*4 + 0, cb)) = w;
  w.x = (vr0.x >> 16) | (vr1.x & 0xFFFF0000u);
  w.y = (vr2.x >> 16) | (vr3.x & 0xFFFF0000u);
  *(uint2*)(VTs + SWZ256(vdg*4 + 1, cb)) = w;
  w.x = (vr0.y & 0xFFFFu) | ((vr1.y & 0xFFFFu) << 16);
  w.y = (vr2.y & 0xFFFFu) | ((vr3.y & 0xFFFFu) << 16);
  *(uint2*)(VTs + SWZ256(vdg*4 + 2, cb)) = w;
  w.x = (vr0.y >> 16) | (vr1.y & 0xFFFF0000u);
  w.y = (vr2.y >> 16) | (vr3.y & 0xFFFF0000u);
  *(uint2*)(VTs + SWZ256(vdg*4 + 3, cb)) = w;
}

// ---------------- 4. diagonal causal (fused pair, 8 waves, KVBLK=128) ----------------
__global__ __launch_bounds__(512, 4) void diag_mfma(
    const ushort_t* __restrict__ qb, const ushort_t* __restrict__ kb, const ushort_t* __restrict__ vb,
    float* __restrict__ out, float* __restrict__ lse)
{
  __shared__ __align__(16) char Ks[16384];    // [128 key][64 d]
  __shared__ __align__(16) char VTs[20480];   // [80 d'][128 col']; rows 64..79 = ones
  __shared__ __align__(16) char Ps[8][4096];  // per wave [16 q][128 col']
  const int bid = blockIdx.x;                 // 512 = 8 xcd * 4 inst * 16 pairs
  const int xcd = bid & 7, sl = bid >> 3;
  const int inst = xcd*4 + (sl >> 4);
  const int pi = sl & 15;
  const int h = inst >> 2, tblk = inst & 3;
  const size_t hoff = (size_t)h * NSEQ * D;
  const ushort_t* qh = qb + hoff; const ushort_t* kh = kb + hoff; const ushort_t* vh = vb + hoff;
  const int blkbase = tblk * 2048;
  const int tid = threadIdx.x;
  const int w = tid >> 6, lane = tid & 63;
  const int lo = lane & 15, hi = lane >> 4;
  char* Pw = Ps[w];
  // staging maps (512 threads): K row = 4 threads x 32B (full 128B row)
  const int kr = tid >> 2, kq = tid & 3;
  const int vlo = tid & 15, vdg = (tid >> 4) & 15, vsth = tid >> 8;

  { // ones-column region (rows 64..79), written once
    uint2 one2 = { 0x3F803F80u, 0x3F803F80u };
    *(uint2*)(VTs + 16384 + tid*8) = one2;
  }

  const int qt  = (w < 4) ? (31 - pi) : pi;                 // waves 0-3: long tile
  const int wq  = w & 3;                                    // 16-row group in tile
  const int nkt   = (31 - pi)/2 + 1;                        // loop length (long tile)
  const int mynkt = qt/2 + 1;                               // this wave's tiles
  const int qpos0 = qt*64 + wq*16;

  v8s qf[2];
  {
    const ushort_t* r = qh + (size_t)(blkbase + qpos0 + lo) * D;
    qf[0] = *(const v8s*)(r + hi*8);
    qf[1] = *(const v8s*)(r + 32 + hi*8);
  }
  const v4f vz = {0.0f, 0.0f, 0.0f, 0.0f};
  v4f o[5] = {vz, vz, vz, vz, vz};
  float m[4] = {-INFINITY, -INFINITY, -INFINITY, -INFINITY};

  uint4 kreg0, kreg1; uint2 vr0, vr1, vr2, vr3;
#define DLOAD(kt) { \
    const ushort_t* ksr = kh + (size_t)(blkbase + (kt)*128 + kr)*D + kq*16; \
    kreg0 = *(const uint4*)ksr; \
    kreg1 = *(const uint4*)(ksr + 8); \
    const ushort_t* vs = vh + (size_t)(blkbase + (kt)*128 + vsth*64 + vlo)*D + vdg*4; \
    vr0 = *(const uint2*)(vs); \
    vr1 = *(const uint2*)(vs + 16*D); \
    vr2 = *(const uint2*)(vs + 32*D); \
    vr3 = *(const uint2*)(vs + 48*D); }

  DLOAD(0);
#pragma unroll 1
  for (int kt = 0; kt < nkt; ++kt){
    *(uint4*)(Ks + SWZ(kr, kq*32))      = kreg0;
    *(uint4*)(Ks + SWZ(kr, kq*32 + 16)) = kreg1;
    vt_write(VTs, vr0, vr1, vr2, vr3, vdg, vlo, vsth);
    __syncthreads();
    if (kt + 1 < nkt) DLOAD(kt+1);
    if (kt < mynkt){
      v4f sa[8] = {vz, vz, vz, vz, vz, vz, vz, vz};
      qk8(qf, Ks, lo, hi, sa);
#pragma unroll
      for (int st = 0; st < 8; ++st) sa[st] *= SC2;
      if (kt == mynkt - 1){
#pragma unroll
        for (int st = 0; st < 8; ++st){
          int kpos = kt*128 + st*16 + lo;
#pragma unroll
          for (int reg = 0; reg < 4; ++reg)
            if (kpos > qpos0 + hi*4 + reg) sa[st][reg] = -INFINITY;
        }
      }
      sm_pv8(sa, Pw, VTs, lo, hi, m, o);
    }
    __syncthreads();
  }
#undef DLOAD
#pragma unroll
  for (int reg = 0; reg < 4; ++reg){
    int rw = blkbase + qpos0 + hi*4 + reg;
    float lsum = o[4][reg];
    float inv = 1.0f / lsum;
#pragma unroll
    for (int dt = 0; dt < 4; ++dt)
      out[hoff + (size_t)rw*D + dt*16 + lo] = o[dt][reg] * inv;
    if (lo == 0) lse[h*NSEQ + rw] = m[reg]*LN2F + logf(lsum);
  }
}

// ---------------- 5/6. LSH no-causal + merge, 8 waves, KVBLK=128 ----------------
__device__ __forceinline__ int nc_key(const int* __restrict__ ki, const int* __restrict__ sp,
                                      int qblk, int kt, int pos, int& msk){
  if (kt < 2){ msk = 0; return ki[qblk*256 + kt*128 + pos]; }
  int s = sp[(kt-2)*128 + pos]; msk = ((s >> 8) == qblk) ? 1 : 0; return ki[s];
}

template<int LEVEL>
__global__ __launch_bounds__(512, 4) void nc_mfma(
    const ushort_t* __restrict__ qb, const ushort_t* __restrict__ kb, const ushort_t* __restrict__ vb,
    float* __restrict__ out, float* __restrict__ lse,
    const int* __restrict__ qidx, const int* __restrict__ kidx, const int* __restrict__ samp)
{
  __shared__ __align__(16) char Ks[16384];
  __shared__ __align__(16) char VTs[20480];
  __shared__ __align__(16) char Ps[8][4096];
  __shared__ int kmk[128];
  const int bid = blockIdx.x;
  int inst, jb;
  if (LEVEL == 101){ int xcd = bid & 7, sl = bid >> 3; inst = xcd*2 + (sl >> 4); jb = sl & 15; }
  else             { inst = bid & 7; jb = bid >> 3; }
  const float delta2 = (LEVEL == 101) ? 3.0f : 4.0f;     // log2(2048/256), log2(4096/256)
  const int seglen = (LEVEL == 101) ? 2048 : 4096;
  const int* qi = qidx + inst*seglen;
  const int* ki = kidx + inst*seglen;
  const int* sp = samp + inst*256;
  const int h = (LEVEL == 101) ? (inst >> 1) : inst;
  const int qblk = jb >> 1;                   // sorted 256-block of this 128-row group
  const size_t hoff = (size_t)h * NSEQ * D;
  const ushort_t* qh = qb + hoff; const ushort_t* kh = kb + hoff; const ushort_t* vh = vb + hoff;
  const int tid = threadIdx.x;
  const int w = tid >> 6, lane = tid & 63;
  const int lo = lane & 15, hi = lane >> 4;
  char* Pw = Ps[w];
  const int kr = tid >> 2, kq = tid & 3;
  const int vlo = tid & 15, vdg = (tid >> 4) & 15, vsth = tid >> 8;

  { // ones-column region
    uint2 one2 = { 0x3F803F80u, 0x3F803F80u };
    *(uint2*)(VTs + 16384 + tid*8) = one2;
  }

  int orig[4];
  v8s qf[2];
  {
    int qrl = qi[jb*128 + w*16 + lo];
    const ushort_t* r = qh + (size_t)qrl * D;
    qf[0] = *(const v8s*)(r + hi*8);
    qf[1] = *(const v8s*)(r + 32 + hi*8);
#pragma unroll
    for (int reg = 0; reg < 4; ++reg) orig[reg] = qi[jb*128 + w*16 + hi*4 + reg];
  }
  const v4f vz = {0.0f, 0.0f, 0.0f, 0.0f};
  v4f o[5] = {vz, vz, vz, vz, vz};
  float m[4] = {-INFINITY, -INFINITY, -INFINITY, -INFINITY};

  uint4 kreg0, kreg1; uint2 vr0, vr1, vr2, vr3; int msk;
#define NLOAD(kt) { \
    int krow = nc_key(ki, sp, qblk, kt, kr, msk); \
    const ushort_t* ksr = kh + (size_t)krow*D + kq*16; \
    kreg0 = *(const uint4*)ksr; \
    kreg1 = *(const uint4*)(ksr + 8); \
    int m_; \
    int g0 = nc_key(ki, sp, qblk, kt, vsth*64 + vlo,      m_); \
    int g1 = nc_key(ki, sp, qblk, kt, vsth*64 + 16 + vlo, m_); \
    int g2 = nc_key(ki, sp, qblk, kt, vsth*64 + 32 + vlo, m_); \
    int g3 = nc_key(ki, sp, qblk, kt, vsth*64 + 48 + vlo, m_); \
    vr0 = *(const uint2*)(vh + (size_t)g0*D + vdg*4); \
    vr1 = *(const uint2*)(vh + (size_t)g1*D + vdg*4); \
    vr2 = *(const uint2*)(vh + (size_t)g2*D + vdg*4); \
    vr3 = *(const uint2*)(vh + (size_t)g3*D + vdg*4); }

  NLOAD(0);
#pragma unroll 1
  for (int kt = 0; kt < 4; ++kt){
    *(uint4*)(Ks + SWZ(kr, kq*32))      = kreg0;
    *(uint4*)(Ks + SWZ(kr, kq*32 + 16)) = kreg1;
    if (kq == 0) kmk[kr] = msk;
    vt_write(VTs, vr0, vr1, vr2, vr3, vdg, vlo, vsth);
    __syncthreads();
    if (kt + 1 < 4) NLOAD(kt+1);
    v4f sa[8] = {vz, vz, vz, vz, vz, vz, vz, vz};
    qk8(qf, Ks, lo, hi, sa);
    if (kt < 2){
#pragma unroll
      for (int st = 0; st < 8; ++st) sa[st] *= SC2;
    } else {
#pragma unroll
      for (int st = 0; st < 8; ++st){
        if (kmk[st*16 + lo]) sa[st] = (v4f){-INFINITY, -INFINITY, -INFINITY, -INFINITY};
        else                 sa[st] = sa[st]*SC2 + delta2;
      }
    }
    sm_pv8(sa, Pw, VTs, lo, hi, m, o);
    __syncthreads();
  }
#undef NLOAD
  // merge epilogue (_add_attn)
#pragma unroll
  for (int reg = 0; reg < 4; ++reg){
    int og = orig[reg];
    float lsum = o[4][reg];
    float l1v = lse[h*NSEQ + og];
    float l2v = m[reg]*LN2F + logf(lsum);
    float c = 1.0f / (1.0f + __expf(l2v - l1v));
    float inv = (1.0f - c) / lsum;
#pragma unroll
    for (int dt = 0; dt < 4; ++dt){
      float* ap = out + hoff + (size_t)og*D + dt*16 + lo;
      *ap = c * (*ap) + inv * o[dt][reg];
    }
    if (lo == 0) lse[h*NSEQ + og] = l1v - logf(c + EPSF);
  }
}

// ---------------- launch ----------------
extern "C" void kernel_launch(void* const* d_in, const int* in_sizes, int n_in,
                              void* d_out, int out_size, void* d_ws, size_t ws_size,
                              hipStream_t stream)
{
  const float* q    = (const float*)d_in[0];
  const float* k    = (const float*)d_in[1];
  const float* v    = (const float*)d_in[2];
  const float* proj = (const float*)d_in[3];
  float* out = (float*)d_out;

  char* ws = (char*)d_ws;
  float* lse = (float*)ws;                       // 256 KB
  int* hq   = (int*)(ws + 262144);               // 256 KB
  int* hk   = (int*)(ws + 524288);               // 256 KB
  int* q100 = (int*)(ws + 786432);               // 128 KB
  int* k100 = (int*)(ws + 917504);               // 128 KB
  int* q101 = (int*)(ws + 1048576);              // 128 KB
  int* k101 = (int*)(ws + 1179648);              // 128 KB
  int* s100 = (int*)(ws + 1310720);              // 8 KB
  int* s101 = (int*)(ws + 1318912);              // 16 KB
  ushort_t* qb = (ushort_t*)(ws + 1335296);      // 8 MB each
  ushort_t* kb = qb + (size_t)H*NSEQ*D;
  ushort_t* vb = kb + (size_t)H*NSEQ*D;

  prep_hash    <<<dim3(2048), dim3(256), 0, stream>>>(q, k, proj, qb, kb, hq, hk);
  prep_v       <<<dim3(2048), dim3(256), 0, stream>>>(v, vb);
  sample_kernel<<<dim3(24),   dim3(256), 0, stream>>>(s100, s101);
  sort_kernel  <<<dim3(48),   dim3(128), 0, stream>>>(hq, hk, q100, k100, q101, k101);
  diag_mfma    <<<dim3(512),  dim3(512), 0, stream>>>(qb, kb, vb, out, lse);
  nc_mfma<101> <<<dim3(256),  dim3(512), 0, stream>>>(qb, kb, vb, out, lse, q101, k101, s101);
  nc_mfma<100> <<<dim3(256),  dim3(512), 0, stream>>>(qb, kb, vb, out, lse, q100, k100, s100);
}